// Round 6
// baseline (238.957 us; speedup 1.0000x reference)
//
#include <hip/hip_runtime.h>
#include <hip/hip_bf16.h>

#define D 128            // D_IN == D_OUT == 128
#define D4 32            // D/4 float4s per row
#define CHUNK 6144       // edges per hist / bscatter block
#define MAXB 2048        // max buckets => n_nodes <= 131072 for fast path
#define NSEG 8           // scan segments over the chunk axis
#define SL 4096          // LDS srcs-list capacity per bucket (ints, 16KB)

typedef __attribute__((ext_vector_type(8))) short bf16x8;
typedef __attribute__((ext_vector_type(8))) unsigned short ushort8;
typedef __attribute__((ext_vector_type(4))) float f32x4;

// float -> bf16 round-to-nearest-even
static __device__ __forceinline__ unsigned short f2bf(float f) {
    unsigned u = __float_as_uint(f);
    u += 0x7FFFu + ((u >> 16) & 1u);
    return (unsigned short)(u >> 16);
}
static __device__ __forceinline__ float bf2f(unsigned short u) {
    return __uint_as_float(((unsigned)u) << 16);
}

// ---------------------------------------------------------------------------
// One-time W transpose+convert: Wt[c][k] = bf16(W[k][c])  (c-major, 32KB).
// ---------------------------------------------------------------------------
__global__ __launch_bounds__(256) void wcvt_kernel(
    const float* __restrict__ W, unsigned short* __restrict__ Wt)
{
    const int idx = blockIdx.x * 256 + threadIdx.x;   // float4 over 128x32
    const float4 w = ((const float4*)W)[idx];
    const int k = idx >> 5;
    const int c = (idx & 31) * 4;
    Wt[(c + 0) * 128 + k] = f2bf(w.x);
    Wt[(c + 1) * 128 + k] = f2bf(w.y);
    Wt[(c + 2) * 128 + k] = f2bf(w.z);
    Wt[(c + 3) * 128 + k] = f2bf(w.w);
}

// ---------------------------------------------------------------------------
// FAT kernel: two independent roles in one launch (no grid sync needed).
//  blocks [0, GB):      GEMM via bf16 MFMA, 128-row tile, 512 thr = 8 waves.
//                       A direct from global (in-reg cvt); Bs from Wt; C
//                       routed through LDS for coalesced ushort8 stores.
//  blocks [GB, GB+EB):  hist role (512 thr): LDS bucket histogram of a
//                       CHUNK of dst -> H[g][*]; block GB zeroes hwb pad row.
// LDS is a union; the 34.8KB gemm allocation caps both roles at 4 blk/CU x
// 8 waves = 32 waves/CU (the hw max) -- no occupancy loss vs separate.
// ---------------------------------------------------------------------------
__global__ __launch_bounds__(512) void fat_kernel(
    const float* __restrict__ h, const unsigned short* __restrict__ Wt,
    const float* __restrict__ norm, unsigned short* __restrict__ hwb,
    const int* __restrict__ dst, int* __restrict__ H,
    int n_nodes, int n_edges, int GB)
{
    __shared__ union {
        unsigned short Bs[128 * 136];   // gemm: [col][k] bf16 W^T; later C
        int lbh[MAXB];                  // hist: bucket counters
    } sm;

    const int t = threadIdx.x;

    if ((int)blockIdx.x < GB) {
        // ---------------- GEMM role ----------------
        const int row0 = blockIdx.x * 128;

        #pragma unroll
        for (int i = 0; i < 4; ++i) {
            const int idx = t + 512 * i;           // ushort8 index over 128x16
            const int c = idx >> 4;
            const int k8 = idx & 15;
            *(ushort8*)&sm.Bs[c * 136 + k8 * 8] = ((const ushort8*)Wt)[idx];
        }
        __syncthreads();

        const int wv = t >> 6;
        const int lane = t & 63;
        const int m = lane & 15;
        const int quad = lane >> 4;

        long gra = row0 + wv * 16 + m;             // A-fragment source row
        if (gra >= n_nodes) gra = n_nodes - 1;
        const float* hrow = h + gra * D;

        f32x4 acc[8];
        #pragma unroll
        for (int nt = 0; nt < 8; ++nt) { f32x4 z = {0.f, 0.f, 0.f, 0.f}; acc[nt] = z; }

        #pragma unroll
        for (int kt = 0; kt < 4; ++kt) {
            const float4 a0 = *(const float4*)(hrow + kt * 32 + quad * 8);
            const float4 a1 = *(const float4*)(hrow + kt * 32 + quad * 8 + 4);
            bf16x8 af;
            unsigned short* ap = (unsigned short*)&af;
            ap[0] = f2bf(a0.x); ap[1] = f2bf(a0.y); ap[2] = f2bf(a0.z); ap[3] = f2bf(a0.w);
            ap[4] = f2bf(a1.x); ap[5] = f2bf(a1.y); ap[6] = f2bf(a1.z); ap[7] = f2bf(a1.w);
            #pragma unroll
            for (int nt = 0; nt < 8; ++nt) {
                const bf16x8 bfr = *(const bf16x8*)&sm.Bs[(nt * 16 + m) * 136 + kt * 32 + quad * 8];
                acc[nt] = __builtin_amdgcn_mfma_f32_16x16x32_bf16(af, bfr, acc[nt], 0, 0, 0);
            }
        }

        float nv[4];
        #pragma unroll
        for (int i = 0; i < 4; ++i) {
            const int gr = row0 + wv * 16 + quad * 4 + i;
            nv[i] = (gr < n_nodes) ? norm[gr] : 0.f;
        }

        __syncthreads();                           // all waves done reading Bs
        #pragma unroll
        for (int nt = 0; nt < 8; ++nt) {
            #pragma unroll
            for (int i = 0; i < 4; ++i) {
                const int r = wv * 16 + quad * 4 + i;     // 0..127 in-block row
                sm.Bs[r * 136 + nt * 16 + m] = f2bf(acc[nt][i] * nv[i]);
            }
        }
        __syncthreads();

        #pragma unroll
        for (int i2 = 0; i2 < 4; ++i2) {
            const int idx = t + 512 * i2;          // ushort8 over 128x16
            const int r = idx >> 4;
            const int c8 = idx & 15;
            const int gr = row0 + r;
            if (gr < n_nodes)
                *(ushort8*)&hwb[(size_t)gr * D + c8 * 8] =
                    *(const ushort8*)&sm.Bs[r * 136 + c8 * 8];
        }
    } else {
        // ---------------- hist role ----------------
        const int g = blockIdx.x - GB;
        for (int i = t; i < MAXB; i += 512) sm.lbh[i] = 0;
        if (g == 0 && t < 32) {
            ushort4 z; z.x = z.y = z.z = z.w = 0;
            ((ushort4*)(hwb + (size_t)n_nodes * D))[t] = z;   // dummy pad row
        }
        __syncthreads();
        const int e0 = g * CHUNK;
        const int e1 = min(e0 + CHUNK, n_edges);
        for (int e = e0 + t; e < e1; e += 512) {
            atomicAdd(&sm.lbh[dst[e] >> 6], 1);
        }
        __syncthreads();
        for (int i = t; i < MAXB; i += 512) {
            H[(size_t)g * MAXB + i] = sm.lbh[i];
        }
    }
}

// ---------------------------------------------------------------------------
// chunkscan_local: single H pass per (segment, bucket): local exclusive
// prefix over the segment's chunks -> CO (relative), segment total -> PS.
// ---------------------------------------------------------------------------
__global__ __launch_bounds__(256) void chunkscan_local_kernel(
    const int* __restrict__ H, int* __restrict__ CO, int* __restrict__ PS,
    int eb)
{
    const int b = blockIdx.x * 256 + threadIdx.x;
    const int seg = blockIdx.y;
    const int glen = (eb + NSEG - 1) / NSEG;
    const int g0 = seg * glen;
    const int g1 = min(g0 + glen, eb);
    int run = 0;
    for (int g = g0; g < g1; ++g) {
        CO[(size_t)g * MAXB + b] = run;
        run += H[(size_t)g * MAXB + b];
    }
    PS[seg * MAXB + b] = run;
}

// ---------------------------------------------------------------------------
// bucket_scan (1 block): sum PS segments -> exclusive bucket scan -> boff,
// plus per-segment bases SB[sg][b].
// ---------------------------------------------------------------------------
__global__ __launch_bounds__(256) void bucket_scan_kernel(
    const int* __restrict__ PS, int* __restrict__ boff, int* __restrict__ SB)
{
    __shared__ int tmp[256];
    const int t = threadIdx.x;
    int v[8];
    int s = 0;
    #pragma unroll
    for (int k = 0; k < 8; ++k) {
        const int i = t * 8 + k;
        int c = 0;
        #pragma unroll
        for (int sg = 0; sg < NSEG; ++sg) c += PS[sg * MAXB + i];
        v[k] = c; s += c;
    }
    tmp[t] = s;
    __syncthreads();
    for (int ofs = 1; ofs < 256; ofs <<= 1) {
        int x = (t >= ofs) ? tmp[t - ofs] : 0;
        __syncthreads();
        tmp[t] += x;
        __syncthreads();
    }
    int run = tmp[t] - s;
    #pragma unroll
    for (int k = 0; k < 8; ++k) {
        const int i = t * 8 + k;
        boff[i] = run;
        int sb = run;
        #pragma unroll
        for (int sg = 0; sg < NSEG; ++sg) {
            SB[sg * MAXB + i] = sb;
            sb += PS[sg * MAXB + i];
        }
        run += v[k];
    }
    if (t == 255) boff[MAXB] = run;
}

// ---------------------------------------------------------------------------
// bscatter (1024 thr): atomic-free window bases = SB[seg][b] + CO[g][b];
// LDS-ranked scatter of packed records (src | (dst&63)<<17) into ebuf.
// ---------------------------------------------------------------------------
__global__ __launch_bounds__(1024) void bscatter_kernel(
    const int* __restrict__ src, const int* __restrict__ dst,
    const int* __restrict__ CO, const int* __restrict__ SB,
    unsigned int* __restrict__ ebuf, int n_edges, int eb)
{
    __shared__ int lbh[MAXB];
    __shared__ int lofs[MAXB];
    const int t = threadIdx.x;
    const int g = blockIdx.x;
    const int glen = (eb + NSEG - 1) / NSEG;
    const int seg = g / glen;
    for (int i = t; i < MAXB; i += 1024) {
        lbh[i] = 0;
        lofs[i] = SB[seg * MAXB + i] + CO[(size_t)g * MAXB + i];
    }
    __syncthreads();
    const int e0 = g * CHUNK;
    const int e1 = min(e0 + CHUNK, n_edges);
    for (int e = e0 + t; e < e1; e += 1024) {
        const int d = dst[e];
        const int bk = d >> 6;
        const int r = atomicAdd(&lbh[bk], 1);
        ebuf[lofs[bk] + r] = (unsigned)src[e] | ((unsigned)(d & 63) << 17);
    }
}

// ---------------------------------------------------------------------------
// fillagg: one block per bucket (64 nodes, 256 thr). Count -> 64-lane padded
// wave-scan -> ranked scatter into LDS srcs list (global arena fallback) ->
// x8-padded register aggregation, out = agg*norm + bias.
// ---------------------------------------------------------------------------
__global__ __launch_bounds__(256) void fillagg_kernel(
    const unsigned int* __restrict__ ebuf, const int* __restrict__ boff,
    int* __restrict__ srcs_g, const unsigned short* __restrict__ hwb,
    const float* __restrict__ norm, const float* __restrict__ bias,
    float* __restrict__ out, int n_nodes)
{
    __shared__ int slds[SL];
    __shared__ int lcnt[64];
    __shared__ int lcur[64];
    __shared__ int loff[64];
    const int t = threadIdx.x;
    const int b = blockIdx.x;
    const int gn0 = b * 64;

    if (t < 64) lcnt[t] = 0;
    __syncthreads();
    const int w0 = boff[b], w1 = boff[b + 1];
    const int wlen = w1 - w0;
    const bool uselds = (wlen + 480) <= SL;     // pads(448) + margin(32)
    const int gbase = w0 + 448 * b;             // global arena fallback base

    for (int e = w0 + t; e < w1; e += 256) {
        atomicAdd(&lcnt[(ebuf[e] >> 17) & 63], 1);
    }
    __syncthreads();
    if (t < 64) {
        const int c = lcnt[t];
        const int p = (c + 7) & ~7;             // degree padded to x8
        int x = p;
        #pragma unroll
        for (int ofs = 1; ofs < 64; ofs <<= 1) {
            const int y = __shfl_up(x, ofs, 64);
            if (t >= ofs) x += y;
        }
        const int base = x - p;                 // bucket-local exclusive scan
        lcur[t] = base;
        loff[t] = base;
    }
    __syncthreads();
    for (int e = w0 + t; e < w1; e += 256) {
        const unsigned rec = ebuf[e];
        const int loc = (rec >> 17) & 63;
        const int pos = atomicAdd(&lcur[loc], 1);
        const int sv = (int)(rec & 0x1FFFFu);
        if (uselds) slds[pos] = sv; else srcs_g[gbase + pos] = sv;
    }
    for (int w = t; w < 512; w += 256) {
        const int ln = w >> 3, k = w & 7;
        const int gn = gn0 + ln;
        if (gn < n_nodes) {
            const int c = lcnt[ln];
            const int pad = (8 - (c & 7)) & 7;
            if (k < pad) {
                const int pos = loff[ln] + c + k;
                if (uselds) slds[pos] = n_nodes; else srcs_g[gbase + pos] = n_nodes;
            }
        }
    }
    __syncthreads();

    // aggregation: 8 groups x 32 lanes; each group handles 8 nodes
    const ushort4* hw4 = (const ushort4*)hwb;
    const int grp = t >> 5;
    const int l = t & 31;
    const float4 bs = ((const float4*)bias)[l];
    for (int nn = 0; nn < 8; ++nn) {
        const int loc = grp * 8 + nn;
        const int gn = gn0 + loc;
        if (gn >= n_nodes) continue;
        const int start = loff[loc];
        const int deg = lcnt[loc];
        const int nb8 = (deg + 7) >> 3;
        float4 acc; acc.x = acc.y = acc.z = acc.w = 0.f;
        int myidx = 0;
        for (int bb = 0; bb < nb8; ++bb) {
            const int q = bb & 3;
            if (q == 0) {
                const int ri = start + bb * 8 + l;
                myidx = uselds ? slds[ri] : srcs_g[gbase + ri];
            }
            ushort4 v[8];
            #pragma unroll
            for (int jj = 0; jj < 8; ++jj) {
                const int s = __shfl(myidx, q * 8 + jj, 32);
                v[jj] = hw4[(long)s * D4 + l];
            }
            #pragma unroll
            for (int jj = 0; jj < 8; ++jj) {
                acc.x += bf2f(v[jj].x);
                acc.y += bf2f(v[jj].y);
                acc.z += bf2f(v[jj].z);
                acc.w += bf2f(v[jj].w);
            }
        }
        const float nv = norm[gn];
        float4 o;
        o.x = acc.x * nv + bs.x;
        o.y = acc.y * nv + bs.y;
        o.z = acc.z * nv + bs.z;
        o.w = acc.w * nv + bs.w;
        ((float4*)out)[(long)gn * D4 + l] = o;
    }
}

// ---------------------------------------------------------------------------
// Fallback path: atomic scatter from bf16 hwb + finalize (ws too small).
// ---------------------------------------------------------------------------
__global__ __launch_bounds__(256) void scatter_kernel(
    const unsigned short* __restrict__ hwb, const int* __restrict__ src,
    const int* __restrict__ dst, float* __restrict__ out, int n_edges)
{
    const int idx = blockIdx.x * 256 + threadIdx.x;
    if (idx >= n_edges * D4) return;
    const int e = idx >> 5;
    const int g = idx & 31;
    const int s = src[e];
    const int d = dst[e];
    const ushort4 v = ((const ushort4*)hwb)[(long)s * D4 + g];
    float* o = out + (long)d * D + g * 4;
    atomicAdd(o + 0, bf2f(v.x));
    atomicAdd(o + 1, bf2f(v.y));
    atomicAdd(o + 2, bf2f(v.z));
    atomicAdd(o + 3, bf2f(v.w));
}

__global__ __launch_bounds__(256) void finalize_kernel(
    float* __restrict__ out, const float* __restrict__ norm,
    const float* __restrict__ bias, int n_nodes)
{
    const int idx = blockIdx.x * 256 + threadIdx.x;
    if (idx >= n_nodes * D4) return;
    const int n = idx >> 5;
    const int g = idx & 31;
    float4 v = ((float4*)out)[idx];
    const float nv = norm[n];
    const float4 b = ((const float4*)bias)[g];
    v.x = v.x * nv + b.x;
    v.y = v.y * nv + b.y;
    v.z = v.z * nv + b.z;
    v.w = v.w * nv + b.w;
    ((float4*)out)[idx] = v;
}

extern "C" void kernel_launch(void* const* d_in, const int* in_sizes, int n_in,
                              void* d_out, int out_size, void* d_ws, size_t ws_size,
                              hipStream_t stream) {
    const float* h    = (const float*)d_in[0];
    const float* norm = (const float*)d_in[1];
    const int*   src  = (const int*)d_in[2];
    const int*   dst  = (const int*)d_in[3];
    const float* W    = (const float*)d_in[4];
    const float* bias = (const float*)d_in[5];
    float* out = (float*)d_out;

    const int n_nodes = in_sizes[1];
    const int n_edges = in_sizes[2];

    const int NBUCK = (n_nodes + 63) >> 6;           // buckets (64 nodes each)
    const int EB    = (n_edges + CHUNK - 1) / CHUNK; // edge chunks
    const int GB    = (n_nodes + 127) / 128;         // gemm tiles
    const int srcs_len = n_edges + 448 * NBUCK + 64; // bucket-local pad bound

    // ---- workspace layout (256B aligned) ----
    size_t p = 0;
    auto take = [&](size_t bytes) {
        size_t cur = p;
        p += (bytes + 255) & ~(size_t)255;
        return cur;
    };
    const size_t hwb_off  = take(((size_t)n_nodes + 1) * D * sizeof(unsigned short));
    const size_t wt_off   = take((size_t)D * D * sizeof(unsigned short));
    const size_t srcs_off = take((size_t)srcs_len * sizeof(int));
    const size_t ebuf_off = take((size_t)n_edges * sizeof(unsigned int));
    const size_t boff_off = take((MAXB + 1) * sizeof(int));
    const size_t H_off    = take((size_t)EB * MAXB * sizeof(int));
    const size_t PS_off   = take((size_t)NSEG * MAXB * sizeof(int));
    const size_t SB_off   = take((size_t)NSEG * MAXB * sizeof(int));
    const size_t CO_off   = take((size_t)EB * MAXB * sizeof(int));
    const size_t needed = p;

    char* ws = (char*)d_ws;
    unsigned short* hwb = (unsigned short*)(ws + hwb_off);
    unsigned short* Wt  = (unsigned short*)(ws + wt_off);

    // one-time W -> bf16 W^T (gemm role consumes it next launch)
    wcvt_kernel<<<16, 256, 0, stream>>>(W, Wt);

    if (ws_size >= needed && NBUCK <= MAXB && n_nodes <= 131072 && EB <= 1024) {
        int* srcs  = (int*)(ws + srcs_off);
        unsigned int* ebuf = (unsigned int*)(ws + ebuf_off);
        int* boff  = (int*)(ws + boff_off);
        int* H     = (int*)(ws + H_off);
        int* PS    = (int*)(ws + PS_off);
        int* SBp   = (int*)(ws + SB_off);
        int* CO    = (int*)(ws + CO_off);

        // gemm || hist in one launch (independent roles)
        fat_kernel<<<GB + EB, 512, 0, stream>>>(h, Wt, norm, hwb, dst, H,
                                                n_nodes, n_edges, GB);
        chunkscan_local_kernel<<<dim3(MAXB / 256, NSEG), 256, 0, stream>>>(H, CO, PS, EB);
        bucket_scan_kernel<<<1, 256, 0, stream>>>(PS, boff, SBp);
        bscatter_kernel<<<EB, 1024, 0, stream>>>(src, dst, CO, SBp, ebuf, n_edges, EB);
        fillagg_kernel<<<NBUCK, 256, 0, stream>>>(ebuf, boff, srcs, hwb, norm, bias,
                                                  out, n_nodes);
    } else {
        // gemm only (EB=0 -> no hist blocks), then atomic fallback
        fat_kernel<<<GB, 512, 0, stream>>>(h, Wt, norm, hwb, dst, (int*)nullptr,
                                           n_nodes, n_edges, GB);
        hipMemsetAsync(d_out, 0, (size_t)out_size * sizeof(float), stream);
        const int work = n_edges * D4;
        scatter_kernel<<<(work + 255) / 256, 256, 0, stream>>>(hwb, src, dst, out, n_edges);
        const int work2 = n_nodes * D4;
        finalize_kernel<<<(work2 + 255) / 256, 256, 0, stream>>>(out, norm, bias, n_nodes);
    }
}

// Round 7
// 227.441 us; speedup vs baseline: 1.0506x; 1.0506x over previous
//
#include <hip/hip_runtime.h>
#include <hip/hip_bf16.h>
#include <hip/hip_cooperative_groups.h>

namespace cg = cooperative_groups;

#define D 128            // D_IN == D_OUT == 128
#define D4 32            // D/4 float4s per row
#define CHUNK 6400       // edges per hist/bscatter chunk => EB=250 <= 256 CUs
#define MAXB 2048        // max buckets => n_nodes <= 131072 for fast path
#define NSEG 8           // scan segments over the chunk axis
#define SL 4096          // LDS srcs-list capacity per bucket (ints, 16KB)

typedef __attribute__((ext_vector_type(8))) short bf16x8;
typedef __attribute__((ext_vector_type(8))) unsigned short ushort8;
typedef __attribute__((ext_vector_type(4))) float f32x4;

// float -> bf16 round-to-nearest-even
static __device__ __forceinline__ unsigned short f2bf(float f) {
    unsigned u = __float_as_uint(f);
    u += 0x7FFFu + ((u >> 16) & 1u);
    return (unsigned short)(u >> 16);
}
static __device__ __forceinline__ float bf2f(unsigned short u) {
    return __uint_as_float(((unsigned)u) << 16);
}

// ---------------------------------------------------------------------------
// One-time W transpose+convert: Wt[c][k] = bf16(W[k][c])  (c-major, 32KB).
// ---------------------------------------------------------------------------
__global__ __launch_bounds__(256) void wcvt_kernel(
    const float* __restrict__ W, unsigned short* __restrict__ Wt)
{
    const int idx = blockIdx.x * 256 + threadIdx.x;   // float4 over 128x32
    const float4 w = ((const float4*)W)[idx];
    const int k = idx >> 5;
    const int c = (idx & 31) * 4;
    Wt[(c + 0) * 128 + k] = f2bf(w.x);
    Wt[(c + 1) * 128 + k] = f2bf(w.y);
    Wt[(c + 2) * 128 + k] = f2bf(w.z);
    Wt[(c + 3) * 128 + k] = f2bf(w.w);
}

// ---------------------------------------------------------------------------
// GEMM via bf16 MFMA (proven R5 config): hwb[n,:] = bf16((h[n,:] @ W)*norm).
// 128-row tile, 512 thr = 8 waves; A direct from global (in-reg cvt);
// Bs from Wt; C routed through LDS for coalesced ushort8 stores.
// ---------------------------------------------------------------------------
__global__ __launch_bounds__(512) void gemm_mfma_kernel(
    const float* __restrict__ h, const unsigned short* __restrict__ Wt,
    const float* __restrict__ norm, unsigned short* __restrict__ hwb,
    int n_nodes)
{
    __shared__ unsigned short Bs[128 * 136];   // [col][k] bf16 (W^T); later C

    const int t = threadIdx.x;
    const int row0 = blockIdx.x * 128;

    #pragma unroll
    for (int i = 0; i < 4; ++i) {
        const int idx = t + 512 * i;           // ushort8 index over 128x16
        const int c = idx >> 4;
        const int k8 = idx & 15;
        *(ushort8*)&Bs[c * 136 + k8 * 8] = ((const ushort8*)Wt)[idx];
    }
    __syncthreads();

    const int wv = t >> 6;
    const int lane = t & 63;
    const int m = lane & 15;
    const int quad = lane >> 4;

    long gra = row0 + wv * 16 + m;             // A-fragment source row
    if (gra >= n_nodes) gra = n_nodes - 1;
    const float* hrow = h + gra * D;

    f32x4 acc[8];
    #pragma unroll
    for (int nt = 0; nt < 8; ++nt) { f32x4 z = {0.f, 0.f, 0.f, 0.f}; acc[nt] = z; }

    #pragma unroll
    for (int kt = 0; kt < 4; ++kt) {
        const float4 a0 = *(const float4*)(hrow + kt * 32 + quad * 8);
        const float4 a1 = *(const float4*)(hrow + kt * 32 + quad * 8 + 4);
        bf16x8 af;
        unsigned short* ap = (unsigned short*)&af;
        ap[0] = f2bf(a0.x); ap[1] = f2bf(a0.y); ap[2] = f2bf(a0.z); ap[3] = f2bf(a0.w);
        ap[4] = f2bf(a1.x); ap[5] = f2bf(a1.y); ap[6] = f2bf(a1.z); ap[7] = f2bf(a1.w);
        #pragma unroll
        for (int nt = 0; nt < 8; ++nt) {
            const bf16x8 bfr = *(const bf16x8*)&Bs[(nt * 16 + m) * 136 + kt * 32 + quad * 8];
            acc[nt] = __builtin_amdgcn_mfma_f32_16x16x32_bf16(af, bfr, acc[nt], 0, 0, 0);
        }
    }

    float nv[4];
    #pragma unroll
    for (int i = 0; i < 4; ++i) {
        const int gr = row0 + wv * 16 + quad * 4 + i;
        nv[i] = (gr < n_nodes) ? norm[gr] : 0.f;
    }

    __syncthreads();                           // all waves done reading Bs
    #pragma unroll
    for (int nt = 0; nt < 8; ++nt) {
        #pragma unroll
        for (int i = 0; i < 4; ++i) {
            const int r = wv * 16 + quad * 4 + i;     // 0..127 in-block row
            Bs[r * 136 + nt * 16 + m] = f2bf(acc[nt][i] * nv[i]);
        }
    }
    __syncthreads();

    #pragma unroll
    for (int i2 = 0; i2 < 4; ++i2) {
        const int idx = t + 512 * i2;          // ushort8 over 128x16
        const int r = idx >> 4;
        const int c8 = idx & 15;
        const int gr = row0 + r;
        if (gr < n_nodes)
            *(ushort8*)&hwb[(size_t)gr * D + c8 * 8] =
                *(const ushort8*)&Bs[r * 136 + c8 * 8];
    }
}

// ---------------------------------------------------------------------------
// TIER 1: cooperative kernel for the whole post-gemm pipeline. 1024 thr,
// NO min-waves clamp (VGPRs free), 17KB LDS union -> co-resident even at
// 1 block/CU (EB<=256). Phases (grid.sync between):
//  P1 hist -> 2a PS -> 2b boff/SB (block 0) -> 2c CO (absolute) ->
//  P3 bscatter -> P4 per-bucket fill+aggregate (grid-stride).
// ---------------------------------------------------------------------------
__global__ __launch_bounds__(1024) void coop_edge_kernel(
    const int* __restrict__ src, const int* __restrict__ dst,
    int* __restrict__ H, int* __restrict__ PS, int* __restrict__ SB,
    int* __restrict__ boff, int* __restrict__ CO,
    unsigned int* __restrict__ ebuf, int* __restrict__ srcs_g,
    const unsigned short* __restrict__ hwb,
    const float* __restrict__ norm, const float* __restrict__ bias,
    float* __restrict__ out,
    int n_edges, int n_nodes, int EB, int NBUCK)
{
    __shared__ int smem[SL + 192];   // phase-aliased: hist/tmp/scatter/fill

    cg::grid_group grid = cg::this_grid();
    const int t = threadIdx.x;
    const int g = blockIdx.x;
    const int gid = g * 1024 + t;
    const int glen = (EB + NSEG - 1) / NSEG;
    const int e0 = g * CHUNK;
    const int e1 = min(e0 + CHUNK, n_edges);

    // ---- P1: per-chunk bucket histogram -> H[g][*] ----
    {
        int* lbh = smem;
        for (int i = t; i < MAXB; i += 1024) lbh[i] = 0;
        if (g == 0 && t < 32) {
            ushort4 z; z.x = z.y = z.z = z.w = 0;
            ((ushort4*)(hwb + (size_t)n_nodes * D))[t] = z;   // dummy pad row
        }
        __syncthreads();
        for (int e = e0 + t; e < e1; e += 1024)
            atomicAdd(&lbh[dst[e] >> 6], 1);
        __syncthreads();
        for (int i = t; i < MAXB; i += 1024) H[(size_t)g * MAXB + i] = lbh[i];
    }
    grid.sync();

    // ---- 2a: PS[seg][c] = segment column sums of H ----
    if (gid < NSEG * MAXB) {
        const int seg = gid >> 11;
        const int c = gid & (MAXB - 1);
        const int g0 = seg * glen, g1 = min(g0 + glen, EB);
        int s = 0;
        for (int gg = g0; gg < g1; ++gg) s += H[(size_t)gg * MAXB + c];
        PS[seg * MAXB + c] = s;
    }
    grid.sync();

    // ---- 2b: block 0 scans bucket totals -> boff; per-seg bases -> SB ----
    if (g == 0) {
        int* tmp = smem;
        const int cA = 2 * t, cB = 2 * t + 1;
        int va = 0, vb = 0;
        #pragma unroll
        for (int sg = 0; sg < NSEG; ++sg) { va += PS[sg * MAXB + cA]; vb += PS[sg * MAXB + cB]; }
        tmp[t] = va + vb;
        __syncthreads();
        for (int ofs = 1; ofs < 1024; ofs <<= 1) {
            const int x = (t >= ofs) ? tmp[t - ofs] : 0;
            __syncthreads();
            tmp[t] += x;
            __syncthreads();
        }
        const int run = tmp[t] - (va + vb);
        boff[cA] = run;
        boff[cB] = run + va;
        if (t == 1023) boff[MAXB] = tmp[1023];
        int sb = run;
        #pragma unroll
        for (int sg = 0; sg < NSEG; ++sg) { SB[sg * MAXB + cA] = sb; sb += PS[sg * MAXB + cA]; }
        sb = run + va;
        #pragma unroll
        for (int sg = 0; sg < NSEG; ++sg) { SB[sg * MAXB + cB] = sb; sb += PS[sg * MAXB + cB]; }
    }
    grid.sync();

    // ---- 2c: CO[g][c] = absolute base of (chunk g, bucket c) window ----
    if (gid < NSEG * MAXB) {
        const int seg = gid >> 11;
        const int c = gid & (MAXB - 1);
        const int g0 = seg * glen, g1 = min(g0 + glen, EB);
        int run = SB[seg * MAXB + c];
        for (int gg = g0; gg < g1; ++gg) {
            CO[(size_t)gg * MAXB + c] = run;
            run += H[(size_t)gg * MAXB + c];
        }
    }
    grid.sync();

    // ---- P3: atomic-free bucket-major scatter into ebuf ----
    {
        int* lbh = smem;
        int* lofs = smem + MAXB;
        for (int i = t; i < MAXB; i += 1024) {
            lbh[i] = 0;
            lofs[i] = CO[(size_t)g * MAXB + i];
        }
        __syncthreads();
        for (int e = e0 + t; e < e1; e += 1024) {
            const int d = dst[e];
            const int bk = d >> 6;
            const int r = atomicAdd(&lbh[bk], 1);
            ebuf[lofs[bk] + r] = (unsigned)src[e] | ((unsigned)(d & 63) << 17);
        }
    }
    grid.sync();

    // ---- P4: per-bucket fill + aggregation (grid-stride over buckets) ----
    {
        int* slds = smem;
        int* lcnt = smem + SL;
        int* lcur = smem + SL + 64;
        int* loff = smem + SL + 128;
        const ushort4* hw4 = (const ushort4*)hwb;
        const int grp = t >> 5;
        const int l = t & 31;
        const float4 bs = ((const float4*)bias)[l];

        for (int bkt = g; bkt < NBUCK; bkt += gridDim.x) {
            __syncthreads();                    // protect LDS reuse across buckets
            if (t < 64) lcnt[t] = 0;
            __syncthreads();
            const int w0 = boff[bkt], w1 = boff[bkt + 1];
            const int wlen = w1 - w0;
            const bool uselds = (wlen + 480) <= SL;   // pads(448)+margin(32)
            const int gbase = w0 + 448 * bkt;         // global arena fallback
            const int gn0 = bkt * 64;

            for (int e = w0 + t; e < w1; e += 1024)
                atomicAdd(&lcnt[(ebuf[e] >> 17) & 63], 1);
            __syncthreads();
            if (t < 64) {
                const int c = lcnt[t];
                const int p = (c + 7) & ~7;           // degree padded to x8
                int x = p;
                #pragma unroll
                for (int ofs = 1; ofs < 64; ofs <<= 1) {
                    const int y = __shfl_up(x, ofs, 64);
                    if (t >= ofs) x += y;
                }
                const int base = x - p;               // local exclusive scan
                lcur[t] = base;
                loff[t] = base;
            }
            __syncthreads();
            for (int e = w0 + t; e < w1; e += 1024) {
                const unsigned rec = ebuf[e];
                const int loc = (rec >> 17) & 63;
                const int pos = atomicAdd(&lcur[loc], 1);
                const int sv = (int)(rec & 0x1FFFFu);
                if (uselds) slds[pos] = sv; else srcs_g[gbase + pos] = sv;
            }
            for (int w = t; w < 512; w += 1024) {
                const int ln = w >> 3, k = w & 7;
                const int gn = gn0 + ln;
                if (gn < n_nodes) {
                    const int c = lcnt[ln];
                    const int pad = (8 - (c & 7)) & 7;
                    if (k < pad) {
                        const int pos = loff[ln] + c + k;
                        if (uselds) slds[pos] = n_nodes; else srcs_g[gbase + pos] = n_nodes;
                    }
                }
            }
            __syncthreads();

            // 32 groups x 32 lanes; each group aggregates 2 nodes
            #pragma unroll
            for (int nn = 0; nn < 2; ++nn) {
                const int loc = grp * 2 + nn;
                const int gn = gn0 + loc;
                if (gn >= n_nodes) continue;
                const int start = loff[loc];
                const int deg = lcnt[loc];
                const int nb8 = (deg + 7) >> 3;
                float4 acc; acc.x = acc.y = acc.z = acc.w = 0.f;
                int myidx = 0;
                for (int bb = 0; bb < nb8; ++bb) {
                    const int q = bb & 3;
                    if (q == 0) {
                        const int ri = start + bb * 8 + l;
                        myidx = uselds ? slds[ri] : srcs_g[gbase + ri];
                    }
                    ushort4 v[8];
                    #pragma unroll
                    for (int jj = 0; jj < 8; ++jj) {
                        const int s = __shfl(myidx, q * 8 + jj, 32);
                        v[jj] = hw4[(long)s * D4 + l];
                    }
                    #pragma unroll
                    for (int jj = 0; jj < 8; ++jj) {
                        acc.x += bf2f(v[jj].x);
                        acc.y += bf2f(v[jj].y);
                        acc.z += bf2f(v[jj].z);
                        acc.w += bf2f(v[jj].w);
                    }
                }
                const float nv = norm[gn];
                float4 o;
                o.x = acc.x * nv + bs.x;
                o.y = acc.y * nv + bs.y;
                o.z = acc.z * nv + bs.z;
                o.w = acc.w * nv + bs.w;
                ((float4*)out)[(long)gn * D4 + l] = o;
            }
        }
    }
}

// ---------------------------------------------------------------------------
// TIER 2 fallback: the verified R5 multi-kernel chain.
// ---------------------------------------------------------------------------
__global__ __launch_bounds__(1024) void hist_kernel(
    const int* __restrict__ dst, int* __restrict__ H,
    unsigned short* __restrict__ hwb, int n_edges, int n_nodes)
{
    __shared__ int lbh[MAXB];
    const int t = threadIdx.x;
    const int g = blockIdx.x;
    for (int i = t; i < MAXB; i += 1024) lbh[i] = 0;
    if (g == 0 && t < 32) {
        ushort4 z; z.x = z.y = z.z = z.w = 0;
        ((ushort4*)(hwb + (size_t)n_nodes * D))[t] = z;
    }
    __syncthreads();
    const int e0 = g * CHUNK;
    const int e1 = min(e0 + CHUNK, n_edges);
    for (int e = e0 + t; e < e1; e += 1024) {
        atomicAdd(&lbh[dst[e] >> 6], 1);
    }
    __syncthreads();
    for (int i = t; i < MAXB; i += 1024) {
        H[(size_t)g * MAXB + i] = lbh[i];
    }
}

__global__ __launch_bounds__(256) void chunkscan_local_kernel(
    const int* __restrict__ H, int* __restrict__ CO, int* __restrict__ PS,
    int eb)
{
    const int b = blockIdx.x * 256 + threadIdx.x;
    const int seg = blockIdx.y;
    const int glen = (eb + NSEG - 1) / NSEG;
    const int g0 = seg * glen;
    const int g1 = min(g0 + glen, eb);
    int run = 0;
    for (int g = g0; g < g1; ++g) {
        CO[(size_t)g * MAXB + b] = run;
        run += H[(size_t)g * MAXB + b];
    }
    PS[seg * MAXB + b] = run;
}

__global__ __launch_bounds__(256) void bucket_scan_kernel(
    const int* __restrict__ PS, int* __restrict__ boff, int* __restrict__ SB)
{
    __shared__ int tmp[256];
    const int t = threadIdx.x;
    int v[8];
    int s = 0;
    #pragma unroll
    for (int k = 0; k < 8; ++k) {
        const int i = t * 8 + k;
        int c = 0;
        #pragma unroll
        for (int sg = 0; sg < NSEG; ++sg) c += PS[sg * MAXB + i];
        v[k] = c; s += c;
    }
    tmp[t] = s;
    __syncthreads();
    for (int ofs = 1; ofs < 256; ofs <<= 1) {
        int x = (t >= ofs) ? tmp[t - ofs] : 0;
        __syncthreads();
        tmp[t] += x;
        __syncthreads();
    }
    int run = tmp[t] - s;
    #pragma unroll
    for (int k = 0; k < 8; ++k) {
        const int i = t * 8 + k;
        boff[i] = run;
        int sb = run;
        #pragma unroll
        for (int sg = 0; sg < NSEG; ++sg) {
            SB[sg * MAXB + i] = sb;
            sb += PS[sg * MAXB + i];
        }
        run += v[k];
    }
    if (t == 255) boff[MAXB] = run;
}

__global__ __launch_bounds__(1024) void bscatter_kernel(
    const int* __restrict__ src, const int* __restrict__ dst,
    const int* __restrict__ CO, const int* __restrict__ SB,
    unsigned int* __restrict__ ebuf, int n_edges, int eb)
{
    __shared__ int lbh[MAXB];
    __shared__ int lofs[MAXB];
    const int t = threadIdx.x;
    const int g = blockIdx.x;
    const int glen = (eb + NSEG - 1) / NSEG;
    const int seg = g / glen;
    for (int i = t; i < MAXB; i += 1024) {
        lbh[i] = 0;
        lofs[i] = SB[seg * MAXB + i] + CO[(size_t)g * MAXB + i];
    }
    __syncthreads();
    const int e0 = g * CHUNK;
    const int e1 = min(e0 + CHUNK, n_edges);
    for (int e = e0 + t; e < e1; e += 1024) {
        const int d = dst[e];
        const int bk = d >> 6;
        const int r = atomicAdd(&lbh[bk], 1);
        ebuf[lofs[bk] + r] = (unsigned)src[e] | ((unsigned)(d & 63) << 17);
    }
}

__global__ __launch_bounds__(256) void fillagg_kernel(
    const unsigned int* __restrict__ ebuf, const int* __restrict__ boff,
    int* __restrict__ srcs_g, const unsigned short* __restrict__ hwb,
    const float* __restrict__ norm, const float* __restrict__ bias,
    float* __restrict__ out, int n_nodes)
{
    __shared__ int slds[SL];
    __shared__ int lcnt[64];
    __shared__ int lcur[64];
    __shared__ int loff[64];
    const int t = threadIdx.x;
    const int b = blockIdx.x;
    const int gn0 = b * 64;

    if (t < 64) lcnt[t] = 0;
    __syncthreads();
    const int w0 = boff[b], w1 = boff[b + 1];
    const int wlen = w1 - w0;
    const bool uselds = (wlen + 480) <= SL;
    const int gbase = w0 + 448 * b;

    for (int e = w0 + t; e < w1; e += 256) {
        atomicAdd(&lcnt[(ebuf[e] >> 17) & 63], 1);
    }
    __syncthreads();
    if (t < 64) {
        const int c = lcnt[t];
        const int p = (c + 7) & ~7;
        int x = p;
        #pragma unroll
        for (int ofs = 1; ofs < 64; ofs <<= 1) {
            const int y = __shfl_up(x, ofs, 64);
            if (t >= ofs) x += y;
        }
        const int base = x - p;
        lcur[t] = base;
        loff[t] = base;
    }
    __syncthreads();
    for (int e = w0 + t; e < w1; e += 256) {
        const unsigned rec = ebuf[e];
        const int loc = (rec >> 17) & 63;
        const int pos = atomicAdd(&lcur[loc], 1);
        const int sv = (int)(rec & 0x1FFFFu);
        if (uselds) slds[pos] = sv; else srcs_g[gbase + pos] = sv;
    }
    for (int w = t; w < 512; w += 256) {
        const int ln = w >> 3, k = w & 7;
        const int gn = gn0 + ln;
        if (gn < n_nodes) {
            const int c = lcnt[ln];
            const int pad = (8 - (c & 7)) & 7;
            if (k < pad) {
                const int pos = loff[ln] + c + k;
                if (uselds) slds[pos] = n_nodes; else srcs_g[gbase + pos] = n_nodes;
            }
        }
    }
    __syncthreads();

    const ushort4* hw4 = (const ushort4*)hwb;
    const int grp = t >> 5;
    const int l = t & 31;
    const float4 bs = ((const float4*)bias)[l];
    for (int nn = 0; nn < 8; ++nn) {
        const int loc = grp * 8 + nn;
        const int gn = gn0 + loc;
        if (gn >= n_nodes) continue;
        const int start = loff[loc];
        const int deg = lcnt[loc];
        const int nb8 = (deg + 7) >> 3;
        float4 acc; acc.x = acc.y = acc.z = acc.w = 0.f;
        int myidx = 0;
        for (int bb = 0; bb < nb8; ++bb) {
            const int q = bb & 3;
            if (q == 0) {
                const int ri = start + bb * 8 + l;
                myidx = uselds ? slds[ri] : srcs_g[gbase + ri];
            }
            ushort4 v[8];
            #pragma unroll
            for (int jj = 0; jj < 8; ++jj) {
                const int s = __shfl(myidx, q * 8 + jj, 32);
                v[jj] = hw4[(long)s * D4 + l];
            }
            #pragma unroll
            for (int jj = 0; jj < 8; ++jj) {
                acc.x += bf2f(v[jj].x);
                acc.y += bf2f(v[jj].y);
                acc.z += bf2f(v[jj].z);
                acc.w += bf2f(v[jj].w);
            }
        }
        const float nv = norm[gn];
        float4 o;
        o.x = acc.x * nv + bs.x;
        o.y = acc.y * nv + bs.y;
        o.z = acc.z * nv + bs.z;
        o.w = acc.w * nv + bs.w;
        ((float4*)out)[(long)gn * D4 + l] = o;
    }
}

// ---------------------------------------------------------------------------
// TIER 3 fallback: atomic scatter + finalize.
// ---------------------------------------------------------------------------
__global__ __launch_bounds__(256) void scatter_kernel(
    const unsigned short* __restrict__ hwb, const int* __restrict__ src,
    const int* __restrict__ dst, float* __restrict__ out, int n_edges)
{
    const int idx = blockIdx.x * 256 + threadIdx.x;
    if (idx >= n_edges * D4) return;
    const int e = idx >> 5;
    const int g = idx & 31;
    const int s = src[e];
    const int d = dst[e];
    const ushort4 v = ((const ushort4*)hwb)[(long)s * D4 + g];
    float* o = out + (long)d * D + g * 4;
    atomicAdd(o + 0, bf2f(v.x));
    atomicAdd(o + 1, bf2f(v.y));
    atomicAdd(o + 2, bf2f(v.z));
    atomicAdd(o + 3, bf2f(v.w));
}

__global__ __launch_bounds__(256) void finalize_kernel(
    float* __restrict__ out, const float* __restrict__ norm,
    const float* __restrict__ bias, int n_nodes)
{
    const int idx = blockIdx.x * 256 + threadIdx.x;
    if (idx >= n_nodes * D4) return;
    const int n = idx >> 5;
    const int g = idx & 31;
    float4 v = ((float4*)out)[idx];
    const float nv = norm[n];
    const float4 b = ((const float4*)bias)[g];
    v.x = v.x * nv + b.x;
    v.y = v.y * nv + b.y;
    v.z = v.z * nv + b.z;
    v.w = v.w * nv + b.w;
    ((float4*)out)[idx] = v;
}

extern "C" void kernel_launch(void* const* d_in, const int* in_sizes, int n_in,
                              void* d_out, int out_size, void* d_ws, size_t ws_size,
                              hipStream_t stream) {
    const float* h    = (const float*)d_in[0];
    const float* norm = (const float*)d_in[1];
    const int*   src  = (const int*)d_in[2];
    const int*   dst  = (const int*)d_in[3];
    const float* W    = (const float*)d_in[4];
    const float* bias = (const float*)d_in[5];
    float* out = (float*)d_out;

    const int n_nodes = in_sizes[1];
    const int n_edges = in_sizes[2];

    const int NBUCK = (n_nodes + 63) >> 6;           // buckets (64 nodes each)
    const int EB    = (n_edges + CHUNK - 1) / CHUNK; // edge chunks (250)
    const int srcs_len = n_edges + 448 * NBUCK + 64; // bucket-local pad bound

    // ---- workspace layout (256B aligned) ----
    size_t p = 0;
    auto take = [&](size_t bytes) {
        size_t cur = p;
        p += (bytes + 255) & ~(size_t)255;
        return cur;
    };
    const size_t hwb_off  = take(((size_t)n_nodes + 1) * D * sizeof(unsigned short));
    const size_t wt_off   = take((size_t)D * D * sizeof(unsigned short));
    const size_t srcs_off = take((size_t)srcs_len * sizeof(int));
    const size_t ebuf_off = take((size_t)n_edges * sizeof(unsigned int));
    const size_t boff_off = take((MAXB + 1) * sizeof(int));
    const size_t H_off    = take((size_t)EB * MAXB * sizeof(int));
    const size_t PS_off   = take((size_t)NSEG * MAXB * sizeof(int));
    const size_t SB_off   = take((size_t)NSEG * MAXB * sizeof(int));
    const size_t CO_off   = take((size_t)EB * MAXB * sizeof(int));
    const size_t needed = p;

    char* ws = (char*)d_ws;
    unsigned short* hwb = (unsigned short*)(ws + hwb_off);
    unsigned short* Wt  = (unsigned short*)(ws + wt_off);

    // 1) one-time W -> bf16 W^T, then hwb = bf16((h @ W) * norm) via MFMA
    wcvt_kernel<<<16, 256, 0, stream>>>(W, Wt);
    gemm_mfma_kernel<<<(n_nodes + 127) / 128, 512, 0, stream>>>(h, Wt, norm, hwb, n_nodes);

    // cooperative-residency check (host-side, cached)
    static int s_max_coop_blocks = -1;
    if (s_max_coop_blocks < 0) {
        int nb = 0;
        if (hipOccupancyMaxActiveBlocksPerMultiprocessor(&nb, coop_edge_kernel, 1024, 0)
            != hipSuccess) nb = 0;
        int dev = 0;
        hipGetDevice(&dev);
        int ncu = 0;
        if (hipDeviceGetAttribute(&ncu, hipDeviceAttributeMultiprocessorCount, dev)
            != hipSuccess) ncu = 0;
        s_max_coop_blocks = nb * ncu;
    }

    const bool ws_ok = (ws_size >= needed) && (NBUCK <= MAXB) && (n_nodes <= 131072);
    const bool coop_ok = ws_ok && EB >= 16 && EB <= 512 && EB <= s_max_coop_blocks;

    if (coop_ok) {
        int* srcs  = (int*)(ws + srcs_off);
        unsigned int* ebuf = (unsigned int*)(ws + ebuf_off);
        int* boff  = (int*)(ws + boff_off);
        int* H     = (int*)(ws + H_off);
        int* PS    = (int*)(ws + PS_off);
        int* SBp   = (int*)(ws + SB_off);
        int* CO    = (int*)(ws + CO_off);

        int ne = n_edges, nn = n_nodes, eb = EB, nbk = NBUCK;
        void* args[] = {
            (void*)&src, (void*)&dst, (void*)&H, (void*)&PS, (void*)&SBp,
            (void*)&boff, (void*)&CO, (void*)&ebuf, (void*)&srcs, (void*)&hwb,
            (void*)&norm, (void*)&bias, (void*)&out,
            (void*)&ne, (void*)&nn, (void*)&eb, (void*)&nbk
        };
        hipLaunchCooperativeKernel((void*)coop_edge_kernel, dim3(EB), dim3(1024),
                                   args, 0, stream);
    } else if (ws_ok && EB <= 1024) {
        int* srcs  = (int*)(ws + srcs_off);
        unsigned int* ebuf = (unsigned int*)(ws + ebuf_off);
        int* boff  = (int*)(ws + boff_off);
        int* H     = (int*)(ws + H_off);
        int* PS    = (int*)(ws + PS_off);
        int* SBp   = (int*)(ws + SB_off);
        int* CO    = (int*)(ws + CO_off);

        hist_kernel<<<EB, 1024, 0, stream>>>(dst, H, hwb, n_edges, n_nodes);
        chunkscan_local_kernel<<<dim3(MAXB / 256, NSEG), 256, 0, stream>>>(H, CO, PS, EB);
        bucket_scan_kernel<<<1, 256, 0, stream>>>(PS, boff, SBp);
        bscatter_kernel<<<EB, 1024, 0, stream>>>(src, dst, CO, SBp, ebuf, n_edges, EB);
        fillagg_kernel<<<NBUCK, 256, 0, stream>>>(ebuf, boff, srcs, hwb, norm, bias,
                                                  out, n_nodes);
    } else {
        hipMemsetAsync(d_out, 0, (size_t)out_size * sizeof(float), stream);
        const int work = n_edges * D4;
        scatter_kernel<<<(work + 255) / 256, 256, 0, stream>>>(hwb, src, dst, out, n_edges);
        const int work2 = n_nodes * D4;
        finalize_kernel<<<(work2 + 255) / 256, 256, 0, stream>>>(out, norm, bias, n_nodes);
    }
}